// Round 2
// baseline (436.501 us; speedup 1.0000x reference)
//
#include <hip/hip_runtime.h>
#include <hip/hip_bf16.h>

// Problem sizes (fixed by the reference)
#define N_NODES 10000
#define N_EDGES 160000

// ---------------------------------------------------------------------------
// Workspace layout (bytes) — fixed part is ~11.6 MB; `mix` takes the rest and
// is chunked to whatever ws_size allows (adaptive, deterministic per call).
//   counts  : int[N_NODES]        @ 0
//   offsets : int[N_NODES]        @ OFF_OFFSETS
//   cursors : int[N_NODES]        @ OFF_CURSORS
//   order   : int[N_EDGES]        @ OFF_ORDER    (edge ids sorted by receiver)
//   yw      : float[N_EDGES*16]   @ OFF_Y        (Y1[3],Y2[5],Y3[7],pad — CSR-permuted)
//   ssort   : int[N_EDGES]        @ OFF_SSORT    (senders, CSR-permuted)
//   mix     : float[CHUNK*256]    @ OFF_MIX      (CSR-permuted, chunked)
// ---------------------------------------------------------------------------
#define OFF_OFFSETS  40064
#define OFF_CURSORS  80128
#define OFF_ORDER    120192
#define OFF_Y        760320
#define OFF_SSORT    11000320
#define OFF_MIX      11640320

// ---------------- CSR build ----------------
__global__ void khist(const int* __restrict__ recv, int* __restrict__ counts) {
    int e = blockIdx.x * 256 + threadIdx.x;
    atomicAdd(&counts[recv[e]], 1);
}

__global__ void kscan(const int* __restrict__ counts, int* __restrict__ offsets,
                      int* __restrict__ cursors) {
    __shared__ int lds[1024];
    __shared__ int carry;
    if (threadIdx.x == 0) carry = 0;
    __syncthreads();
    for (int base = 0; base < N_NODES; base += 1024) {
        int i = base + threadIdx.x;
        int v = (i < N_NODES) ? counts[i] : 0;
        lds[threadIdx.x] = v;
        __syncthreads();
        int x = v;
        for (int off = 1; off < 1024; off <<= 1) {
            int t = (threadIdx.x >= off) ? lds[threadIdx.x - off] : 0;
            __syncthreads();
            x += t;
            lds[threadIdx.x] = x;
            __syncthreads();
        }
        int c = carry;                 // uniform
        if (i < N_NODES) { offsets[i] = c + x - v; cursors[i] = c + x - v; }
        __syncthreads();
        if (threadIdx.x == 1023) carry = c + x;   // x == tile-inclusive total at tid 1023
        __syncthreads();
    }
}

__global__ void korder(const int* __restrict__ recv, int* __restrict__ cursors,
                       int* __restrict__ order) {
    int e = blockIdx.x * 256 + threadIdx.x;
    int r = recv[e];
    int p = atomicAdd(&cursors[r], 1);
    order[p] = e;
}

// ---------------- CSR-permuted spherical harmonics + sender permute ----------------
__global__ void kyp(const float* __restrict__ vec, const int* __restrict__ order,
                    const int* __restrict__ senders,
                    float* __restrict__ yw, int* __restrict__ ssort) {
    int p = blockIdx.x * 256 + threadIdx.x;
    int e = order[p];
    ssort[p] = senders[e];
    float x = vec[e * 3 + 0], y = vec[e * 3 + 1], z = vec[e * 3 + 2];
    float nrm = sqrtf(x * x + y * y + z * z);
    float d = 1.f / (nrm + 1e-12f);
    x *= d; y *= d; z *= d;
    const float s3  = 1.7320508075688772f;
    const float s5  = 2.2360679774997896f;
    const float s15 = 3.8729833462074170f;
    const float c33 = 2.0916500663351889f;   // sqrt(35/8)
    const float c32 = 10.246950765959598f;   // sqrt(105)
    const float c31 = 1.6201851746019651f;   // sqrt(21/8)
    const float c30 = 1.3228756555322954f;   // 0.5*sqrt(7)
    float x2 = x * x, y2 = y * y, z2 = z * z;
    float4 a, b, c, dd;
    a.x = s3 * y;  a.y = s3 * z;  a.z = s3 * x;           // Y1
    a.w = s15 * x * y;                                     // Y2[0]
    b.x = s15 * y * z;
    b.y = 0.5f * s5 * (3.f * z2 - 1.f);
    b.z = s15 * x * z;
    b.w = 0.5f * s15 * (x2 - y2);
    c.x = c33 * y * (3.f * x2 - y2);                       // Y3
    c.y = c32 * x * y * z;
    c.z = c31 * y * (5.f * z2 - 1.f);
    c.w = c30 * z * (5.f * z2 - 3.f);
    dd.x = c31 * x * (5.f * z2 - 1.f);
    dd.y = 0.5f * c32 * z * (x2 - y2);
    dd.z = c33 * x * (x2 - 3.f * y2);
    dd.w = 0.f;
    float4* yp = reinterpret_cast<float4*>(yw + (size_t)p * 16);
    yp[0] = a; yp[1] = b; yp[2] = c; yp[3] = dd;
}

// ---------------- fused 4-layer radial MLP -> mix[chunk,256] (CSR order) --------
// lane = output channel; weight column lives in VGPRs (static indices via full
// unroll); activations broadcast from LDS (same-address reads are conflict-free).
// LDS: 2 KB + 16 KB + 16 KB = 34 KB (< 64 KB workgroup limit).
#define ETILE 64
__device__ __forceinline__ float silu(float v) {
    return v / (1.f + expf(-v));
}

__global__ __launch_bounds__(256) void kmlp(const float* __restrict__ radial,
                                            const int* __restrict__ order,
                                            const float* __restrict__ w1,
                                            const float* __restrict__ w2,
                                            const float* __restrict__ w3,
                                            const float* __restrict__ w4,
                                            float* __restrict__ mix, int clo) {
    __shared__ float x0[ETILE * 8];
    __shared__ float hA[ETILE * 64];
    __shared__ float hB[ETILE * 64];
    const int tid  = threadIdx.x;
    const int lane = tid & 63;
    const int wv   = tid >> 6;
    const int pb   = clo + blockIdx.x * ETILE;   // permuted-position base

    // stage radial tile (gathered via order; 32 B per edge)
    #pragma unroll
    for (int r = 0; r < (ETILE * 8) / 256; ++r) {
        int idx = tid + 256 * r;
        int e = order[pb + (idx >> 3)];
        x0[idx] = radial[(size_t)e * 8 + (idx & 7)];
    }
    __syncthreads();
    // After this point hA/hB rows are wave-private (wave wv owns edges
    // [wv*16, wv*16+16)) — no further barriers needed.

    // ---- layer 1 (K=8): h1 = silu((x0 @ w1) / sqrt(8)) -> hA
    {
        float w[8];
        #pragma unroll
        for (int k = 0; k < 8; ++k) w[k] = w1[k * 64 + lane];
        for (int eg = 0; eg < 16; eg += 8) {
            const int e0 = wv * 16 + eg;
            float acc[8];
            #pragma unroll
            for (int j = 0; j < 8; ++j) acc[j] = 0.f;
            #pragma unroll
            for (int kq = 0; kq < 2; ++kq) {
                #pragma unroll
                for (int j = 0; j < 8; ++j) {
                    float4 h = *reinterpret_cast<const float4*>(&x0[(e0 + j) * 8 + kq * 4]);
                    acc[j] += h.x * w[kq * 4 + 0] + h.y * w[kq * 4 + 1] +
                              h.z * w[kq * 4 + 2] + h.w * w[kq * 4 + 3];
                }
            }
            #pragma unroll
            for (int j = 0; j < 8; ++j)
                hA[(e0 + j) * 64 + lane] = silu(acc[j] * 0.35355339059327373f);
        }
    }

    // ---- layer 2 (K=64): h2 = silu((h1 @ w2) / 8) -> hB
    {
        float w[64];
        #pragma unroll
        for (int k = 0; k < 64; ++k) w[k] = w2[k * 64 + lane];
        for (int eg = 0; eg < 16; eg += 8) {
            const int e0 = wv * 16 + eg;
            float acc[8];
            #pragma unroll
            for (int j = 0; j < 8; ++j) acc[j] = 0.f;
            #pragma unroll
            for (int kq = 0; kq < 16; ++kq) {
                #pragma unroll
                for (int j = 0; j < 8; ++j) {
                    float4 h = *reinterpret_cast<const float4*>(&hA[(e0 + j) * 64 + kq * 4]);
                    acc[j] += h.x * w[kq * 4 + 0] + h.y * w[kq * 4 + 1] +
                              h.z * w[kq * 4 + 2] + h.w * w[kq * 4 + 3];
                }
            }
            #pragma unroll
            for (int j = 0; j < 8; ++j)
                hB[(e0 + j) * 64 + lane] = silu(acc[j] * 0.125f);
        }
    }

    // ---- layer 3 (K=64): h3 = silu((h2 @ w3) / 8) -> hA
    {
        float w[64];
        #pragma unroll
        for (int k = 0; k < 64; ++k) w[k] = w3[k * 64 + lane];
        for (int eg = 0; eg < 16; eg += 8) {
            const int e0 = wv * 16 + eg;
            float acc[8];
            #pragma unroll
            for (int j = 0; j < 8; ++j) acc[j] = 0.f;
            #pragma unroll
            for (int kq = 0; kq < 16; ++kq) {
                #pragma unroll
                for (int j = 0; j < 8; ++j) {
                    float4 h = *reinterpret_cast<const float4*>(&hB[(e0 + j) * 64 + kq * 4]);
                    acc[j] += h.x * w[kq * 4 + 0] + h.y * w[kq * 4 + 1] +
                              h.z * w[kq * 4 + 2] + h.w * w[kq * 4 + 3];
                }
            }
            #pragma unroll
            for (int j = 0; j < 8; ++j)
                hA[(e0 + j) * 64 + lane] = silu(acc[j] * 0.125f);
        }
    }

    // ---- layer 4 (K=64, N=256): mix = (h3 @ w4) / 8 -> global (chunk-relative)
    for (int jg = 0; jg < 4; ++jg) {
        float w[64];
        #pragma unroll
        for (int k = 0; k < 64; ++k) w[k] = w4[k * 256 + jg * 64 + lane];
        for (int eg = 0; eg < 16; eg += 8) {
            const int e0 = wv * 16 + eg;
            float acc[8];
            #pragma unroll
            for (int j = 0; j < 8; ++j) acc[j] = 0.f;
            #pragma unroll
            for (int kq = 0; kq < 16; ++kq) {
                #pragma unroll
                for (int j = 0; j < 8; ++j) {
                    float4 h = *reinterpret_cast<const float4*>(&hA[(e0 + j) * 64 + kq * 4]);
                    acc[j] += h.x * w[kq * 4 + 0] + h.y * w[kq * 4 + 1] +
                              h.z * w[kq * 4 + 2] + h.w * w[kq * 4 + 3];
                }
            }
            #pragma unroll
            for (int j = 0; j < 8; ++j)
                mix[(size_t)(blockIdx.x * ETILE + e0 + j) * 256 + jg * 64 + lane] =
                    acc[j] * 0.125f;
        }
    }
}

// ---------------- per-node gather/accumulate (sequential mix/yw/ssort reads) ----
// wave per node; lane = channel; 16 accumulators = one 1024-wide output row.
// out is zero-initialized; the chunk containing a node's first edge stores,
// later chunks accumulate. No __syncthreads (so[wv] is wave-private).
__global__ __launch_bounds__(256) void kgather(const float* __restrict__ mix,
                                               const float* __restrict__ yw,
                                               const int* __restrict__ ssort,
                                               const float* __restrict__ node_feats,
                                               const int* __restrict__ offsets,
                                               const int* __restrict__ counts,
                                               float* __restrict__ out,
                                               int clo, int chi) {
    __shared__ float so[4][1024];
    const int lane = threadIdx.x & 63;
    const int wv   = threadIdx.x >> 6;
    const int n    = blockIdx.x * 4 + wv;   // grid is exactly N_NODES/4

    const int start = offsets[n];
    const int cnt   = counts[n];
    const int end   = start + cnt;
    const int s0    = (start > clo) ? start : clo;
    const int s1    = (end < chi) ? end : chi;

    float a0 = 0.f;
    float a1[3] = {0.f, 0.f, 0.f};
    float a2[5] = {0.f, 0.f, 0.f, 0.f, 0.f};
    float a3[7] = {0.f, 0.f, 0.f, 0.f, 0.f, 0.f, 0.f};

    for (int i = s0; i < s1; ++i) {
        const int snd = __builtin_amdgcn_readfirstlane(ssort[i]);
        const float s = node_feats[snd * 64 + lane];
        const float* mp = mix + (size_t)(i - clo) * 256;
        const float t0 = s * mp[lane];
        const float t1 = s * mp[64 + lane];
        const float t2 = s * mp[128 + lane];
        const float t3 = s * mp[192 + lane];
        const float4* yp = reinterpret_cast<const float4*>(yw + (size_t)i * 16);
        const float4 ya = yp[0], yb = yp[1], yc = yp[2], yd = yp[3];
        a0 += t0;
        a1[0] += t1 * ya.x; a1[1] += t1 * ya.y; a1[2] += t1 * ya.z;
        a2[0] += t2 * ya.w; a2[1] += t2 * yb.x; a2[2] += t2 * yb.y;
        a2[3] += t2 * yb.z; a2[4] += t2 * yb.w;
        a3[0] += t3 * yc.x; a3[1] += t3 * yc.y; a3[2] += t3 * yc.z;
        a3[3] += t3 * yc.w; a3[4] += t3 * yd.x; a3[5] += t3 * yd.y;
        a3[6] += t3 * yd.z;
    }

    // stage irrep-strided layout in LDS (wave-private), then coalesced store
    so[wv][lane] = a0;
    #pragma unroll
    for (int j = 0; j < 3; ++j) so[wv][64  + lane * 3 + j] = a1[j];
    #pragma unroll
    for (int j = 0; j < 5; ++j) so[wv][256 + lane * 5 + j] = a2[j];
    #pragma unroll
    for (int j = 0; j < 7; ++j) so[wv][576 + lane * 7 + j] = a3[j];

    if (s1 > s0) {
        float* op = out + (size_t)n * 1024;
        if (start >= clo) {       // this chunk holds the node's first edge
            #pragma unroll
            for (int k = 0; k < 16; ++k)
                op[k * 64 + lane] = so[wv][k * 64 + lane] * 0.25f;   // 1/sqrt(16)
        } else {                  // continuation chunk: accumulate
            #pragma unroll
            for (int k = 0; k < 16; ++k)
                op[k * 64 + lane] += so[wv][k * 64 + lane] * 0.25f;
        }
    }
}

// ---------------- launch ----------------
extern "C" void kernel_launch(void* const* d_in, const int* in_sizes, int n_in,
                              void* d_out, int out_size, void* d_ws, size_t ws_size,
                              hipStream_t stream) {
    const float* vectors    = (const float*)d_in[0];
    const float* node_feats = (const float*)d_in[1];
    const float* radial     = (const float*)d_in[2];
    const float* w1         = (const float*)d_in[3];
    const float* w2         = (const float*)d_in[4];
    const float* w3         = (const float*)d_in[5];
    const float* w4         = (const float*)d_in[6];
    const int*   senders    = (const int*)d_in[7];
    const int*   receivers  = (const int*)d_in[8];
    float*       out        = (float*)d_out;

    char* ws = (char*)d_ws;
    int*   counts  = (int*)(ws);
    int*   offsets = (int*)(ws + OFF_OFFSETS);
    int*   cursors = (int*)(ws + OFF_CURSORS);
    int*   order   = (int*)(ws + OFF_ORDER);
    float* yw      = (float*)(ws + OFF_Y);
    int*   ssort   = (int*)(ws + OFF_SSORT);
    float* mix     = (float*)(ws + OFF_MIX);

    // adaptive mix chunking from ws_size (constant per session -> graph-safe)
    size_t avail = (ws_size > (size_t)OFF_MIX) ? ws_size - (size_t)OFF_MIX : 0;
    long maxE = (long)(avail / (256 * 4));
    maxE -= maxE % 128;
    if (maxE < 128) maxE = 128;          // below ~12 MB ws nothing fits anyway
    if (maxE > N_EDGES) maxE = N_EDGES;
    const int nch = (int)((N_EDGES + maxE - 1) / maxE);

    hipMemsetAsync(counts, 0, N_NODES * sizeof(int), stream);
    hipMemsetAsync(out, 0, (size_t)out_size * sizeof(float), stream);
    khist <<<N_EDGES / 256, 256, 0, stream>>>(receivers, counts);
    kscan <<<1, 1024, 0, stream>>>(counts, offsets, cursors);
    korder<<<N_EDGES / 256, 256, 0, stream>>>(receivers, cursors, order);
    kyp   <<<N_EDGES / 256, 256, 0, stream>>>(vectors, order, senders, yw, ssort);

    for (int c = 0; c < nch; ++c) {
        const int clo = (int)((long)c * maxE);
        const int chi = (int)(((long)clo + maxE < N_EDGES) ? clo + maxE : N_EDGES);
        kmlp   <<<(chi - clo) / ETILE, 256, 0, stream>>>(radial, order, w1, w2, w3, w4,
                                                         mix, clo);
        kgather<<<N_NODES / 4, 256, 0, stream>>>(mix, yw, ssort, node_feats,
                                                 offsets, counts, out, clo, chi);
    }
}

// Round 3
// 316.183 us; speedup vs baseline: 1.3805x; 1.3805x over previous
//
#include <hip/hip_runtime.h>
#include <hip/hip_bf16.h>

// Problem sizes (fixed by the reference)
#define N_NODES 10000
#define N_EDGES 160000

// ---------------------------------------------------------------------------
// Workspace layout (bytes) — fixed part ~11.6 MB; `mix` takes the rest and is
// chunked to whatever ws_size allows (adaptive, deterministic per call).
// ---------------------------------------------------------------------------
#define OFF_OFFSETS  40064
#define OFF_CURSORS  80128
#define OFF_ORDER    120192
#define OFF_Y        760320
#define OFF_SSORT    11000320
#define OFF_MIX      11640320

// ---------------- CSR build ----------------
__global__ void khist(const int* __restrict__ recv, int* __restrict__ counts) {
    int e = blockIdx.x * 256 + threadIdx.x;
    atomicAdd(&counts[recv[e]], 1);
}

__global__ void kscan(const int* __restrict__ counts, int* __restrict__ offsets,
                      int* __restrict__ cursors) {
    __shared__ int lds[1024];
    __shared__ int carry;
    if (threadIdx.x == 0) carry = 0;
    __syncthreads();
    for (int base = 0; base < N_NODES; base += 1024) {
        int i = base + threadIdx.x;
        int v = (i < N_NODES) ? counts[i] : 0;
        lds[threadIdx.x] = v;
        __syncthreads();
        int x = v;
        for (int off = 1; off < 1024; off <<= 1) {
            int t = (threadIdx.x >= off) ? lds[threadIdx.x - off] : 0;
            __syncthreads();
            x += t;
            lds[threadIdx.x] = x;
            __syncthreads();
        }
        int c = carry;                 // uniform
        if (i < N_NODES) { offsets[i] = c + x - v; cursors[i] = c + x - v; }
        __syncthreads();
        if (threadIdx.x == 1023) carry = c + x;
        __syncthreads();
    }
}

__global__ void korder(const int* __restrict__ recv, int* __restrict__ cursors,
                       int* __restrict__ order) {
    int e = blockIdx.x * 256 + threadIdx.x;
    int r = recv[e];
    int p = atomicAdd(&cursors[r], 1);
    order[p] = e;
}

// ---------------- CSR-permuted spherical harmonics + sender permute ------------
__global__ void kyp(const float* __restrict__ vec, const int* __restrict__ order,
                    const int* __restrict__ senders,
                    float* __restrict__ yw, int* __restrict__ ssort) {
    int p = blockIdx.x * 256 + threadIdx.x;
    int e = order[p];
    ssort[p] = senders[e];
    float x = vec[e * 3 + 0], y = vec[e * 3 + 1], z = vec[e * 3 + 2];
    float nrm = sqrtf(x * x + y * y + z * z);
    float d = 1.f / (nrm + 1e-12f);
    x *= d; y *= d; z *= d;
    const float s3  = 1.7320508075688772f;
    const float s5  = 2.2360679774997896f;
    const float s15 = 3.8729833462074170f;
    const float c33 = 2.0916500663351889f;   // sqrt(35/8)
    const float c32 = 10.246950765959598f;   // sqrt(105)
    const float c31 = 1.6201851746019651f;   // sqrt(21/8)
    const float c30 = 1.3228756555322954f;   // 0.5*sqrt(7)
    float x2 = x * x, y2 = y * y, z2 = z * z;
    float4 a, b, c, dd;
    a.x = s3 * y;  a.y = s3 * z;  a.z = s3 * x;           // Y1
    a.w = s15 * x * y;                                     // Y2[0]
    b.x = s15 * y * z;
    b.y = 0.5f * s5 * (3.f * z2 - 1.f);
    b.z = s15 * x * z;
    b.w = 0.5f * s15 * (x2 - y2);
    c.x = c33 * y * (3.f * x2 - y2);                       // Y3
    c.y = c32 * x * y * z;
    c.z = c31 * y * (5.f * z2 - 1.f);
    c.w = c30 * z * (5.f * z2 - 3.f);
    dd.x = c31 * x * (5.f * z2 - 1.f);
    dd.y = 0.5f * c32 * z * (x2 - y2);
    dd.z = c33 * x * (x2 - 3.f * y2);
    dd.w = 0.f;
    float4* yp = reinterpret_cast<float4*>(yw + (size_t)p * 16);
    yp[0] = a; yp[1] = b; yp[2] = c; yp[3] = dd;
}

// ---------------- fused 4-layer radial MLP, register-blocked --------------------
// 1 wave/block, 32 edges/block. Lane = (le in [0,8)) x (ln in [0,8)).
// Lane owns acc[4 edges][8 channels]. Activations: LDS, XOR-quad-swizzled
// (quad' = quad ^ le) -> conflict-free strided reads, 1 read : 32 FMAs.
// Weights: streamed from global (L1-resident, vmem pipe — off the LDS pipe).
#define MTILE 32

__device__ __forceinline__ float silu(float v) {
    return v / (1.f + __expf(-v));
}

template<bool ACT, bool TO_LDS>
__device__ __forceinline__ void layer64(const float* __restrict__ src,   // LDS [32][64] swizzled
                                        const float* __restrict__ W,     // global [64][N]
                                        int N, int nbase, float scale,
                                        float* __restrict__ dst,         // LDS (TO_LDS)
                                        float* __restrict__ gout,        // global (!TO_LDS), pre-offset by nbase
                                        int le, int ln) {
    float acc[4][8];
    #pragma unroll
    for (int j = 0; j < 4; ++j)
        #pragma unroll
        for (int i = 0; i < 8; ++i) acc[j][i] = 0.f;

    #pragma unroll 2
    for (int kq = 0; kq < 16; ++kq) {
        float a[4][4];
        #pragma unroll
        for (int j = 0; j < 4; ++j) {
            float4 t = *reinterpret_cast<const float4*>(
                &src[(le * 4 + j) * 64 + ((kq ^ le) << 2)]);
            a[j][0] = t.x; a[j][1] = t.y; a[j][2] = t.z; a[j][3] = t.w;
        }
        float w[4][8];
        #pragma unroll
        for (int kk = 0; kk < 4; ++kk) {
            const float* wr = W + (size_t)(kq * 4 + kk) * N + nbase + ln * 8;
            float4 t0 = *reinterpret_cast<const float4*>(wr);
            float4 t1 = *reinterpret_cast<const float4*>(wr + 4);
            w[kk][0] = t0.x; w[kk][1] = t0.y; w[kk][2] = t0.z; w[kk][3] = t0.w;
            w[kk][4] = t1.x; w[kk][5] = t1.y; w[kk][6] = t1.z; w[kk][7] = t1.w;
        }
        #pragma unroll
        for (int j = 0; j < 4; ++j)
            #pragma unroll
            for (int kk = 0; kk < 4; ++kk)
                #pragma unroll
                for (int i = 0; i < 8; ++i)
                    acc[j][i] = fmaf(a[j][kk], w[kk][i], acc[j][i]);
    }

    #pragma unroll
    for (int j = 0; j < 4; ++j) {
        #pragma unroll
        for (int t = 0; t < 2; ++t) {
            float v0 = acc[j][t * 4 + 0] * scale;
            float v1 = acc[j][t * 4 + 1] * scale;
            float v2 = acc[j][t * 4 + 2] * scale;
            float v3 = acc[j][t * 4 + 3] * scale;
            float4 o;
            if (ACT) { o.x = silu(v0); o.y = silu(v1); o.z = silu(v2); o.w = silu(v3); }
            else     { o.x = v0; o.y = v1; o.z = v2; o.w = v3; }
            if (TO_LDS) {
                *reinterpret_cast<float4*>(
                    &dst[(le * 4 + j) * 64 + (((2 * ln + t) ^ le) << 2)]) = o;
            } else {
                *reinterpret_cast<float4*>(
                    &gout[(size_t)(le * 4 + j) * 256 + ln * 8 + t * 4]) = o;
            }
        }
    }
}

__global__ __launch_bounds__(64) void kmlp(const float* __restrict__ radial,
                                           const int* __restrict__ order,
                                           const float* __restrict__ w1,
                                           const float* __restrict__ w2,
                                           const float* __restrict__ w3,
                                           const float* __restrict__ w4,
                                           float* __restrict__ mix, int clo) {
    __shared__ float hA[MTILE * 64];
    __shared__ float hB[MTILE * 64];
    const int lane = threadIdx.x;
    const int ln   = lane & 7;
    const int le   = lane >> 3;
    const int pb   = clo + blockIdx.x * MTILE;

    // edge ids for this lane's 4 edges (broadcast across ln)
    int eid[4];
    #pragma unroll
    for (int j = 0; j < 4; ++j) eid[j] = order[pb + le * 4 + j];

    // ---- layer 1 (K=8): acts direct from global; silu((x@w1)/sqrt8) -> hA
    {
        float ax[4][8];
        #pragma unroll
        for (int j = 0; j < 4; ++j) {
            const float* rp = radial + (size_t)eid[j] * 8;
            float4 t0 = *reinterpret_cast<const float4*>(rp);
            float4 t1 = *reinterpret_cast<const float4*>(rp + 4);
            ax[j][0] = t0.x; ax[j][1] = t0.y; ax[j][2] = t0.z; ax[j][3] = t0.w;
            ax[j][4] = t1.x; ax[j][5] = t1.y; ax[j][6] = t1.z; ax[j][7] = t1.w;
        }
        float acc[4][8];
        #pragma unroll
        for (int j = 0; j < 4; ++j)
            #pragma unroll
            for (int i = 0; i < 8; ++i) acc[j][i] = 0.f;
        #pragma unroll
        for (int k = 0; k < 8; ++k) {
            const float* wr = w1 + k * 64 + ln * 8;
            float4 t0 = *reinterpret_cast<const float4*>(wr);
            float4 t1 = *reinterpret_cast<const float4*>(wr + 4);
            float w[8] = {t0.x, t0.y, t0.z, t0.w, t1.x, t1.y, t1.z, t1.w};
            #pragma unroll
            for (int j = 0; j < 4; ++j)
                #pragma unroll
                for (int i = 0; i < 8; ++i)
                    acc[j][i] = fmaf(ax[j][k], w[i], acc[j][i]);
        }
        #pragma unroll
        for (int j = 0; j < 4; ++j) {
            #pragma unroll
            for (int t = 0; t < 2; ++t) {
                float4 o;
                o.x = silu(acc[j][t * 4 + 0] * 0.35355339059327373f);
                o.y = silu(acc[j][t * 4 + 1] * 0.35355339059327373f);
                o.z = silu(acc[j][t * 4 + 2] * 0.35355339059327373f);
                o.w = silu(acc[j][t * 4 + 3] * 0.35355339059327373f);
                *reinterpret_cast<float4*>(
                    &hA[(le * 4 + j) * 64 + (((2 * ln + t) ^ le) << 2)]) = o;
            }
        }
    }

    // ---- layers 2,3: 64->64, silu, LDS->LDS
    layer64<true, true>(hA, w2, 64, 0, 0.125f, hB, nullptr, le, ln);
    layer64<true, true>(hB, w3, 64, 0, 0.125f, hA, nullptr, le, ln);

    // ---- layer 4: 64->256, no act, -> mix (chunk-relative)
    float* gbase = mix + (size_t)(blockIdx.x * MTILE) * 256;
    #pragma unroll
    for (int jg = 0; jg < 4; ++jg)
        layer64<false, false>(hA, w4, 256, jg * 64, 0.125f, nullptr,
                              gbase + jg * 64, le, ln);
}

// ---------------- per-node gather/accumulate (sequential mix/yw/ssort reads) ----
__global__ __launch_bounds__(256) void kgather(const float* __restrict__ mix,
                                               const float* __restrict__ yw,
                                               const int* __restrict__ ssort,
                                               const float* __restrict__ node_feats,
                                               const int* __restrict__ offsets,
                                               const int* __restrict__ counts,
                                               float* __restrict__ out,
                                               int clo, int chi) {
    __shared__ float so[4][1024];
    const int lane = threadIdx.x & 63;
    const int wv   = threadIdx.x >> 6;
    const int n    = blockIdx.x * 4 + wv;   // grid is exactly N_NODES/4

    const int start = offsets[n];
    const int cnt   = counts[n];
    const int end   = start + cnt;
    const int s0    = (start > clo) ? start : clo;
    const int s1    = (end < chi) ? end : chi;

    float a0 = 0.f;
    float a1[3] = {0.f, 0.f, 0.f};
    float a2[5] = {0.f, 0.f, 0.f, 0.f, 0.f};
    float a3[7] = {0.f, 0.f, 0.f, 0.f, 0.f, 0.f, 0.f};

    int i = s0;
    for (; i + 2 <= s1; i += 2) {
        const int sA = ssort[i];
        const int sB = ssort[i + 1];
        const float* mpA = mix + (size_t)(i - clo) * 256;
        const float* mpB = mpA + 256;
        const float fA = node_feats[sA * 64 + lane];
        const float fB = node_feats[sB * 64 + lane];
        const float4* ypA = reinterpret_cast<const float4*>(yw + (size_t)i * 16);
        const float4* ypB = ypA + 4;
        const float4 yaA = ypA[0], ybA = ypA[1], ycA = ypA[2], ydA = ypA[3];
        const float4 yaB = ypB[0], ybB = ypB[1], ycB = ypB[2], ydB = ypB[3];
        const float t0A = fA * mpA[lane],       t0B = fB * mpB[lane];
        const float t1A = fA * mpA[64 + lane],  t1B = fB * mpB[64 + lane];
        const float t2A = fA * mpA[128 + lane], t2B = fB * mpB[128 + lane];
        const float t3A = fA * mpA[192 + lane], t3B = fB * mpB[192 + lane];
        a0 += t0A + t0B;
        a1[0] += t1A * yaA.x + t1B * yaB.x;
        a1[1] += t1A * yaA.y + t1B * yaB.y;
        a1[2] += t1A * yaA.z + t1B * yaB.z;
        a2[0] += t2A * yaA.w + t2B * yaB.w;
        a2[1] += t2A * ybA.x + t2B * ybB.x;
        a2[2] += t2A * ybA.y + t2B * ybB.y;
        a2[3] += t2A * ybA.z + t2B * ybB.z;
        a2[4] += t2A * ybA.w + t2B * ybB.w;
        a3[0] += t3A * ycA.x + t3B * ycB.x;
        a3[1] += t3A * ycA.y + t3B * ycB.y;
        a3[2] += t3A * ycA.z + t3B * ycB.z;
        a3[3] += t3A * ycA.w + t3B * ycB.w;
        a3[4] += t3A * ydA.x + t3B * ydB.x;
        a3[5] += t3A * ydA.y + t3B * ydB.y;
        a3[6] += t3A * ydA.z + t3B * ydB.z;
    }
    if (i < s1) {
        const int sA = ssort[i];
        const float* mpA = mix + (size_t)(i - clo) * 256;
        const float fA = node_feats[sA * 64 + lane];
        const float4* ypA = reinterpret_cast<const float4*>(yw + (size_t)i * 16);
        const float4 yaA = ypA[0], ybA = ypA[1], ycA = ypA[2], ydA = ypA[3];
        const float t0A = fA * mpA[lane];
        const float t1A = fA * mpA[64 + lane];
        const float t2A = fA * mpA[128 + lane];
        const float t3A = fA * mpA[192 + lane];
        a0 += t0A;
        a1[0] += t1A * yaA.x; a1[1] += t1A * yaA.y; a1[2] += t1A * yaA.z;
        a2[0] += t2A * yaA.w; a2[1] += t2A * ybA.x; a2[2] += t2A * ybA.y;
        a2[3] += t2A * ybA.z; a2[4] += t2A * ybA.w;
        a3[0] += t3A * ycA.x; a3[1] += t3A * ycA.y; a3[2] += t3A * ycA.z;
        a3[3] += t3A * ycA.w; a3[4] += t3A * ydA.x; a3[5] += t3A * ydA.y;
        a3[6] += t3A * ydA.z;
    }

    // stage irrep-strided layout in LDS (wave-private), then coalesced store
    so[wv][lane] = a0;
    #pragma unroll
    for (int j = 0; j < 3; ++j) so[wv][64  + lane * 3 + j] = a1[j];
    #pragma unroll
    for (int j = 0; j < 5; ++j) so[wv][256 + lane * 5 + j] = a2[j];
    #pragma unroll
    for (int j = 0; j < 7; ++j) so[wv][576 + lane * 7 + j] = a3[j];

    float* op = out + (size_t)n * 1024;
    if (start >= clo) {           // chunk holds the node's first edge: store
        #pragma unroll
        for (int k = 0; k < 16; ++k)
            op[k * 64 + lane] = so[wv][k * 64 + lane] * 0.25f;   // 1/sqrt(16)
    } else if (s1 > s0) {         // continuation chunk: accumulate
        #pragma unroll
        for (int k = 0; k < 16; ++k)
            op[k * 64 + lane] += so[wv][k * 64 + lane] * 0.25f;
    }
}

// ---------------- launch ----------------
extern "C" void kernel_launch(void* const* d_in, const int* in_sizes, int n_in,
                              void* d_out, int out_size, void* d_ws, size_t ws_size,
                              hipStream_t stream) {
    const float* vectors    = (const float*)d_in[0];
    const float* node_feats = (const float*)d_in[1];
    const float* radial     = (const float*)d_in[2];
    const float* w1         = (const float*)d_in[3];
    const float* w2         = (const float*)d_in[4];
    const float* w3         = (const float*)d_in[5];
    const float* w4         = (const float*)d_in[6];
    const int*   senders    = (const int*)d_in[7];
    const int*   receivers  = (const int*)d_in[8];
    float*       out        = (float*)d_out;

    char* ws = (char*)d_ws;
    int*   counts  = (int*)(ws);
    int*   offsets = (int*)(ws + OFF_OFFSETS);
    int*   cursors = (int*)(ws + OFF_CURSORS);
    int*   order   = (int*)(ws + OFF_ORDER);
    float* yw      = (float*)(ws + OFF_Y);
    int*   ssort   = (int*)(ws + OFF_SSORT);
    float* mix     = (float*)(ws + OFF_MIX);

    // adaptive mix chunking from ws_size (constant per session -> graph-safe)
    size_t avail = (ws_size > (size_t)OFF_MIX) ? ws_size - (size_t)OFF_MIX : 0;
    long maxE = (long)(avail / (256 * 4));
    maxE -= maxE % 128;
    if (maxE < 128) maxE = 128;
    if (maxE > N_EDGES) maxE = N_EDGES;
    const int nch = (int)((N_EDGES + maxE - 1) / maxE);

    hipMemsetAsync(counts, 0, N_NODES * sizeof(int), stream);
    if (nch > 1)
        hipMemsetAsync(out, 0, (size_t)out_size * sizeof(float), stream);
    khist <<<N_EDGES / 256, 256, 0, stream>>>(receivers, counts);
    kscan <<<1, 1024, 0, stream>>>(counts, offsets, cursors);
    korder<<<N_EDGES / 256, 256, 0, stream>>>(receivers, cursors, order);
    kyp   <<<N_EDGES / 256, 256, 0, stream>>>(vectors, order, senders, yw, ssort);

    for (int c = 0; c < nch; ++c) {
        const int clo = (int)((long)c * maxE);
        const int chi = (int)(((long)clo + maxE < N_EDGES) ? clo + maxE : N_EDGES);
        kmlp   <<<(chi - clo) / MTILE, 64, 0, stream>>>(radial, order, w1, w2, w3, w4,
                                                        mix, clo);
        kgather<<<N_NODES / 4, 256, 0, stream>>>(mix, yw, ssort, node_feats,
                                                 offsets, counts, out, clo, chi);
    }
}

// Round 4
// 299.923 us; speedup vs baseline: 1.4554x; 1.0542x over previous
//
#include <hip/hip_runtime.h>
#include <hip/hip_bf16.h>

// Problem sizes (fixed by the reference)
#define N_NODES 10000
#define N_EDGES 160000

// ---------------------------------------------------------------------------
// Workspace layout (bytes) — fixed part ~11.6 MB; `mix` takes the rest and is
// chunked to whatever ws_size allows (adaptive, deterministic per call).
// ---------------------------------------------------------------------------
#define OFF_OFFSETS  40064
#define OFF_CURSORS  80128
#define OFF_ORDER    120192
#define OFF_Y        760320
#define OFF_SSORT    11000320
#define OFF_MIX      11640320

// ---------------- CSR build ----------------
__global__ void khist(const int* __restrict__ recv, int* __restrict__ counts) {
    int e = blockIdx.x * 256 + threadIdx.x;
    atomicAdd(&counts[recv[e]], 1);
}

// 1024-thread shuffle scan: thread t serially scans nodes [t*10, t*10+10),
// wave-level shuffle scan of thread sums, 16 wave totals combined in LDS.
__global__ __launch_bounds__(1024) void kscan(const int* __restrict__ counts,
                                              int* __restrict__ offsets,
                                              int* __restrict__ cursors) {
    __shared__ int wsum[16];
    __shared__ int wpre[16];
    const int tid  = threadIdx.x;
    const int lane = tid & 63;
    const int wv   = tid >> 6;
    const int base = tid * 10;                 // 1024*10 = 10240 >= N_NODES
    int v[10];
    int s = 0;
    #pragma unroll
    for (int j = 0; j < 10; ++j) {
        int i = base + j;
        v[j] = (i < N_NODES) ? counts[i] : 0;
        s += v[j];
    }
    int pre = s;                                // inclusive wave scan
    #pragma unroll
    for (int off = 1; off < 64; off <<= 1) {
        int t = __shfl_up(pre, off);
        if (lane >= off) pre += t;
    }
    if (lane == 63) wsum[wv] = pre;
    __syncthreads();
    if (wv == 0 && lane < 16) {
        int x = wsum[lane];
        int p = x;
        #pragma unroll
        for (int off = 1; off < 16; off <<= 1) {
            int t = __shfl_up(p, off);
            if (lane >= off) p += t;
        }
        wpre[lane] = p - x;                     // exclusive wave prefix
    }
    __syncthreads();
    int excl = wpre[wv] + pre - s;              // exclusive prefix for this thread
    #pragma unroll
    for (int j = 0; j < 10; ++j) {
        int i = base + j;
        if (i < N_NODES) { offsets[i] = excl; cursors[i] = excl; }
        excl += v[j];
    }
}

// ---------------- fused CSR-order + sender permute + spherical harmonics --------
__global__ void kprep(const float* __restrict__ vec, const int* __restrict__ senders,
                      const int* __restrict__ recv, int* __restrict__ cursors,
                      int* __restrict__ order, float* __restrict__ yw,
                      int* __restrict__ ssort) {
    int e = blockIdx.x * 256 + threadIdx.x;
    int r = recv[e];
    int p = atomicAdd(&cursors[r], 1);
    order[p] = e;
    ssort[p] = senders[e];

    float x = vec[e * 3 + 0], y = vec[e * 3 + 1], z = vec[e * 3 + 2];
    float nrm = sqrtf(x * x + y * y + z * z);
    float d = 1.f / (nrm + 1e-12f);
    x *= d; y *= d; z *= d;
    const float s3  = 1.7320508075688772f;
    const float s5  = 2.2360679774997896f;
    const float s15 = 3.8729833462074170f;
    const float c33 = 2.0916500663351889f;   // sqrt(35/8)
    const float c32 = 10.246950765959598f;   // sqrt(105)
    const float c31 = 1.6201851746019651f;   // sqrt(21/8)
    const float c30 = 1.3228756555322954f;   // 0.5*sqrt(7)
    float x2 = x * x, y2 = y * y, z2 = z * z;
    float4 a, b, c, dd;
    a.x = s3 * y;  a.y = s3 * z;  a.z = s3 * x;           // Y1
    a.w = s15 * x * y;                                     // Y2[0]
    b.x = s15 * y * z;
    b.y = 0.5f * s5 * (3.f * z2 - 1.f);
    b.z = s15 * x * z;
    b.w = 0.5f * s15 * (x2 - y2);
    c.x = c33 * y * (3.f * x2 - y2);                       // Y3
    c.y = c32 * x * y * z;
    c.z = c31 * y * (5.f * z2 - 1.f);
    c.w = c30 * z * (5.f * z2 - 3.f);
    dd.x = c31 * x * (5.f * z2 - 1.f);
    dd.y = 0.5f * c32 * z * (x2 - y2);
    dd.z = c33 * x * (x2 - 3.f * y2);
    dd.w = 0.f;
    float4* yp = reinterpret_cast<float4*>(yw + (size_t)p * 16);
    yp[0] = a; yp[1] = b; yp[2] = c; yp[3] = dd;
}

// ---------------- fused 4-layer radial MLP, register-blocked, 8 KB LDS ---------
// 1 wave/block, 32 edges/block. Lane = (le in [0,8)) x (ln in [0,8)).
// Lane owns acc[4 edges][8 channels]. Activations: single LDS buffer,
// XOR-quad-swizzled (quad' = quad ^ le), updated IN-PLACE per layer (all kq
// reads complete before writes; per-wave LDS program order guarantees safety).
// Weights: streamed from global (L1/L2-resident, vmem pipe — off the LDS pipe).
#define MTILE 32

__device__ __forceinline__ float silu(float v) {
    return v / (1.f + __expf(-v));
}

template<bool ACT, bool TO_LDS>
__device__ __forceinline__ void layer64(float* buf,                      // LDS [32][64] swizzled (src, and dst if TO_LDS)
                                        const float* __restrict__ W,     // global [64][N]
                                        int N, int nbase, float scale,
                                        float* __restrict__ gout,        // global (!TO_LDS), pre-offset by nbase
                                        int le, int ln) {
    float acc[4][8];
    #pragma unroll
    for (int j = 0; j < 4; ++j)
        #pragma unroll
        for (int i = 0; i < 8; ++i) acc[j][i] = 0.f;

    #pragma unroll 2
    for (int kq = 0; kq < 16; ++kq) {
        float a[4][4];
        #pragma unroll
        for (int j = 0; j < 4; ++j) {
            float4 t = *reinterpret_cast<const float4*>(
                &buf[(le * 4 + j) * 64 + ((kq ^ le) << 2)]);
            a[j][0] = t.x; a[j][1] = t.y; a[j][2] = t.z; a[j][3] = t.w;
        }
        float w[4][8];
        #pragma unroll
        for (int kk = 0; kk < 4; ++kk) {
            const float* wr = W + (size_t)(kq * 4 + kk) * N + nbase + ln * 8;
            float4 t0 = *reinterpret_cast<const float4*>(wr);
            float4 t1 = *reinterpret_cast<const float4*>(wr + 4);
            w[kk][0] = t0.x; w[kk][1] = t0.y; w[kk][2] = t0.z; w[kk][3] = t0.w;
            w[kk][4] = t1.x; w[kk][5] = t1.y; w[kk][6] = t1.z; w[kk][7] = t1.w;
        }
        #pragma unroll
        for (int j = 0; j < 4; ++j)
            #pragma unroll
            for (int kk = 0; kk < 4; ++kk)
                #pragma unroll
                for (int i = 0; i < 8; ++i)
                    acc[j][i] = fmaf(a[j][kk], w[kk][i], acc[j][i]);
    }

    // fence: keep all LDS reads above, writes below (in-place update)
    asm volatile("" ::: "memory");

    #pragma unroll
    for (int j = 0; j < 4; ++j) {
        #pragma unroll
        for (int t = 0; t < 2; ++t) {
            float v0 = acc[j][t * 4 + 0] * scale;
            float v1 = acc[j][t * 4 + 1] * scale;
            float v2 = acc[j][t * 4 + 2] * scale;
            float v3 = acc[j][t * 4 + 3] * scale;
            float4 o;
            if (ACT) { o.x = silu(v0); o.y = silu(v1); o.z = silu(v2); o.w = silu(v3); }
            else     { o.x = v0; o.y = v1; o.z = v2; o.w = v3; }
            if (TO_LDS) {
                *reinterpret_cast<float4*>(
                    &buf[(le * 4 + j) * 64 + (((2 * ln + t) ^ le) << 2)]) = o;
            } else {
                *reinterpret_cast<float4*>(
                    &gout[(size_t)(le * 4 + j) * 256 + ln * 8 + t * 4]) = o;
            }
        }
    }
}

__global__ __launch_bounds__(64) void kmlp(const float* __restrict__ radial,
                                           const int* __restrict__ order,
                                           const float* __restrict__ w1,
                                           const float* __restrict__ w2,
                                           const float* __restrict__ w3,
                                           const float* __restrict__ w4,
                                           float* __restrict__ mix, int clo) {
    __shared__ float hA[MTILE * 64];   // 8 KB — 20 blocks/CU
    const int lane = threadIdx.x;
    const int ln   = lane & 7;
    const int le   = lane >> 3;
    const int pb   = clo + blockIdx.x * MTILE;

    // edge ids for this lane's 4 edges (same across ln within an le group)
    int eid[4];
    #pragma unroll
    for (int j = 0; j < 4; ++j) eid[j] = order[pb + le * 4 + j];

    // ---- layer 1 (K=8): acts direct from global; silu((x@w1)/sqrt8) -> hA
    {
        float ax[4][8];
        #pragma unroll
        for (int j = 0; j < 4; ++j) {
            const float* rp = radial + (size_t)eid[j] * 8;
            float4 t0 = *reinterpret_cast<const float4*>(rp);
            float4 t1 = *reinterpret_cast<const float4*>(rp + 4);
            ax[j][0] = t0.x; ax[j][1] = t0.y; ax[j][2] = t0.z; ax[j][3] = t0.w;
            ax[j][4] = t1.x; ax[j][5] = t1.y; ax[j][6] = t1.z; ax[j][7] = t1.w;
        }
        float acc[4][8];
        #pragma unroll
        for (int j = 0; j < 4; ++j)
            #pragma unroll
            for (int i = 0; i < 8; ++i) acc[j][i] = 0.f;
        #pragma unroll
        for (int k = 0; k < 8; ++k) {
            const float* wr = w1 + k * 64 + ln * 8;
            float4 t0 = *reinterpret_cast<const float4*>(wr);
            float4 t1 = *reinterpret_cast<const float4*>(wr + 4);
            float w[8] = {t0.x, t0.y, t0.z, t0.w, t1.x, t1.y, t1.z, t1.w};
            #pragma unroll
            for (int j = 0; j < 4; ++j)
                #pragma unroll
                for (int i = 0; i < 8; ++i)
                    acc[j][i] = fmaf(ax[j][k], w[i], acc[j][i]);
        }
        #pragma unroll
        for (int j = 0; j < 4; ++j) {
            #pragma unroll
            for (int t = 0; t < 2; ++t) {
                float4 o;
                o.x = silu(acc[j][t * 4 + 0] * 0.35355339059327373f);
                o.y = silu(acc[j][t * 4 + 1] * 0.35355339059327373f);
                o.z = silu(acc[j][t * 4 + 2] * 0.35355339059327373f);
                o.w = silu(acc[j][t * 4 + 3] * 0.35355339059327373f);
                *reinterpret_cast<float4*>(
                    &hA[(le * 4 + j) * 64 + (((2 * ln + t) ^ le) << 2)]) = o;
            }
        }
    }

    // ---- layers 2,3: 64->64, silu, LDS in-place
    layer64<true, true>(hA, w2, 64, 0, 0.125f, nullptr, le, ln);
    layer64<true, true>(hA, w3, 64, 0, 0.125f, nullptr, le, ln);

    // ---- layer 4: 64->256, no act, -> mix (chunk-relative)
    float* gbase = mix + (size_t)(blockIdx.x * MTILE) * 256;
    #pragma unroll
    for (int jg = 0; jg < 4; ++jg)
        layer64<false, false>(hA, w4, 256, jg * 64, 0.125f, gbase + jg * 64, le, ln);
}

// ---------------- per-node gather/accumulate (sequential mix/yw/ssort reads) ----
__global__ __launch_bounds__(256) void kgather(const float* __restrict__ mix,
                                               const float* __restrict__ yw,
                                               const int* __restrict__ ssort,
                                               const float* __restrict__ node_feats,
                                               const int* __restrict__ offsets,
                                               const int* __restrict__ counts,
                                               float* __restrict__ out,
                                               int clo, int chi) {
    __shared__ float so[4][1024];
    const int lane = threadIdx.x & 63;
    const int wv   = threadIdx.x >> 6;
    const int n    = blockIdx.x * 4 + wv;   // grid is exactly N_NODES/4

    const int start = offsets[n];
    const int cnt   = counts[n];
    const int end   = start + cnt;
    const int s0    = (start > clo) ? start : clo;
    const int s1    = (end < chi) ? end : chi;

    float a0 = 0.f;
    float a1[3] = {0.f, 0.f, 0.f};
    float a2[5] = {0.f, 0.f, 0.f, 0.f, 0.f};
    float a3[7] = {0.f, 0.f, 0.f, 0.f, 0.f, 0.f, 0.f};

    int i = s0;
    for (; i + 2 <= s1; i += 2) {
        const int sA = ssort[i];
        const int sB = ssort[i + 1];
        const float* mpA = mix + (size_t)(i - clo) * 256;
        const float* mpB = mpA + 256;
        const float fA = node_feats[sA * 64 + lane];
        const float fB = node_feats[sB * 64 + lane];
        const float4* ypA = reinterpret_cast<const float4*>(yw + (size_t)i * 16);
        const float4* ypB = ypA + 4;
        const float4 yaA = ypA[0], ybA = ypA[1], ycA = ypA[2], ydA = ypA[3];
        const float4 yaB = ypB[0], ybB = ypB[1], ycB = ypB[2], ydB = ypB[3];
        const float t0A = fA * mpA[lane],       t0B = fB * mpB[lane];
        const float t1A = fA * mpA[64 + lane],  t1B = fB * mpB[64 + lane];
        const float t2A = fA * mpA[128 + lane], t2B = fB * mpB[128 + lane];
        const float t3A = fA * mpA[192 + lane], t3B = fB * mpB[192 + lane];
        a0 += t0A + t0B;
        a1[0] += t1A * yaA.x + t1B * yaB.x;
        a1[1] += t1A * yaA.y + t1B * yaB.y;
        a1[2] += t1A * yaA.z + t1B * yaB.z;
        a2[0] += t2A * yaA.w + t2B * yaB.w;
        a2[1] += t2A * ybA.x + t2B * ybB.x;
        a2[2] += t2A * ybA.y + t2B * ybB.y;
        a2[3] += t2A * ybA.z + t2B * ybB.z;
        a2[4] += t2A * ybA.w + t2B * ybB.w;
        a3[0] += t3A * ycA.x + t3B * ycB.x;
        a3[1] += t3A * ycA.y + t3B * ycB.y;
        a3[2] += t3A * ycA.z + t3B * ycB.z;
        a3[3] += t3A * ycA.w + t3B * ycB.w;
        a3[4] += t3A * ydA.x + t3B * ydB.x;
        a3[5] += t3A * ydA.y + t3B * ydB.y;
        a3[6] += t3A * ydA.z + t3B * ydB.z;
    }
    if (i < s1) {
        const int sA = ssort[i];
        const float* mpA = mix + (size_t)(i - clo) * 256;
        const float fA = node_feats[sA * 64 + lane];
        const float4* ypA = reinterpret_cast<const float4*>(yw + (size_t)i * 16);
        const float4 yaA = ypA[0], ybA = ypA[1], ycA = ypA[2], ydA = ypA[3];
        const float t0A = fA * mpA[lane];
        const float t1A = fA * mpA[64 + lane];
        const float t2A = fA * mpA[128 + lane];
        const float t3A = fA * mpA[192 + lane];
        a0 += t0A;
        a1[0] += t1A * yaA.x; a1[1] += t1A * yaA.y; a1[2] += t1A * yaA.z;
        a2[0] += t2A * yaA.w; a2[1] += t2A * ybA.x; a2[2] += t2A * ybA.y;
        a2[3] += t2A * ybA.z; a2[4] += t2A * ybA.w;
        a3[0] += t3A * ycA.x; a3[1] += t3A * ycA.y; a3[2] += t3A * ycA.z;
        a3[3] += t3A * ycA.w; a3[4] += t3A * ydA.x; a3[5] += t3A * ydA.y;
        a3[6] += t3A * ydA.z;
    }

    // stage irrep-strided layout in LDS (wave-private), then coalesced store
    so[wv][lane] = a0;
    #pragma unroll
    for (int j = 0; j < 3; ++j) so[wv][64  + lane * 3 + j] = a1[j];
    #pragma unroll
    for (int j = 0; j < 5; ++j) so[wv][256 + lane * 5 + j] = a2[j];
    #pragma unroll
    for (int j = 0; j < 7; ++j) so[wv][576 + lane * 7 + j] = a3[j];

    float* op = out + (size_t)n * 1024;
    if (start >= clo) {           // chunk holds the node's first edge: store
        #pragma unroll
        for (int k = 0; k < 16; ++k)
            op[k * 64 + lane] = so[wv][k * 64 + lane] * 0.25f;   // 1/sqrt(16)
    } else if (s1 > s0) {         // continuation chunk: accumulate
        #pragma unroll
        for (int k = 0; k < 16; ++k)
            op[k * 64 + lane] += so[wv][k * 64 + lane] * 0.25f;
    }
}

// ---------------- launch ----------------
extern "C" void kernel_launch(void* const* d_in, const int* in_sizes, int n_in,
                              void* d_out, int out_size, void* d_ws, size_t ws_size,
                              hipStream_t stream) {
    const float* vectors    = (const float*)d_in[0];
    const float* node_feats = (const float*)d_in[1];
    const float* radial     = (const float*)d_in[2];
    const float* w1         = (const float*)d_in[3];
    const float* w2         = (const float*)d_in[4];
    const float* w3         = (const float*)d_in[5];
    const float* w4         = (const float*)d_in[6];
    const int*   senders    = (const int*)d_in[7];
    const int*   receivers  = (const int*)d_in[8];
    float*       out        = (float*)d_out;

    char* ws = (char*)d_ws;
    int*   counts  = (int*)(ws);
    int*   offsets = (int*)(ws + OFF_OFFSETS);
    int*   cursors = (int*)(ws + OFF_CURSORS);
    int*   order   = (int*)(ws + OFF_ORDER);
    float* yw      = (float*)(ws + OFF_Y);
    int*   ssort   = (int*)(ws + OFF_SSORT);
    float* mix     = (float*)(ws + OFF_MIX);

    // adaptive mix chunking from ws_size (constant per session -> graph-safe)
    size_t avail = (ws_size > (size_t)OFF_MIX) ? ws_size - (size_t)OFF_MIX : 0;
    long maxE = (long)(avail / (256 * 4));
    maxE -= maxE % 128;
    if (maxE < 128) maxE = 128;
    if (maxE > N_EDGES) maxE = N_EDGES;
    const int nch = (int)((N_EDGES + maxE - 1) / maxE);

    hipMemsetAsync(counts, 0, N_NODES * sizeof(int), stream);
    if (nch > 1)
        hipMemsetAsync(out, 0, (size_t)out_size * sizeof(float), stream);
    khist <<<N_EDGES / 256, 256, 0, stream>>>(receivers, counts);
    kscan <<<1, 1024, 0, stream>>>(counts, offsets, cursors);
    kprep <<<N_EDGES / 256, 256, 0, stream>>>(vectors, senders, receivers, cursors,
                                              order, yw, ssort);

    for (int c = 0; c < nch; ++c) {
        const int clo = (int)((long)c * maxE);
        const int chi = (int)(((long)clo + maxE < N_EDGES) ? clo + maxE : N_EDGES);
        kmlp   <<<(chi - clo) / MTILE, 64, 0, stream>>>(radial, order, w1, w2, w3, w4,
                                                        mix, clo);
        kgather<<<N_NODES / 4, 256, 0, stream>>>(mix, yw, ssort, node_feats,
                                                 offsets, counts, out, clo, chi);
    }
}

// Round 6
// 292.277 us; speedup vs baseline: 1.4935x; 1.0262x over previous
//
#include <hip/hip_runtime.h>
#include <hip/hip_bf16.h>

// Problem sizes (fixed by the reference)
#define N_NODES 10000
#define N_EDGES 160000

// ---------------------------------------------------------------------------
// Workspace layout (bytes) — fixed part ~11.6 MB; `mix` takes the rest and is
// chunked to whatever ws_size allows (adaptive, deterministic per call).
// ---------------------------------------------------------------------------
#define OFF_OFFSETS  40064
#define OFF_CURSORS  80128
#define OFF_ORDER    120192
#define OFF_Y        760320
#define OFF_SSORT    11000320
#define OFF_MIX      11640320

// ---------------- CSR build ----------------
__global__ void khist(const int* __restrict__ recv, int* __restrict__ counts) {
    int e = blockIdx.x * 256 + threadIdx.x;
    atomicAdd(&counts[recv[e]], 1);
}

// 1024-thread shuffle scan: thread t serially scans nodes [t*10, t*10+10),
// wave-level shuffle scan of thread sums, 16 wave totals combined in LDS.
__global__ __launch_bounds__(1024) void kscan(const int* __restrict__ counts,
                                              int* __restrict__ offsets,
                                              int* __restrict__ cursors) {
    __shared__ int wsum[16];
    __shared__ int wpre[16];
    const int tid  = threadIdx.x;
    const int lane = tid & 63;
    const int wv   = tid >> 6;
    const int base = tid * 10;                 // 1024*10 = 10240 >= N_NODES
    int v[10];
    int s = 0;
    #pragma unroll
    for (int j = 0; j < 10; ++j) {
        int i = base + j;
        v[j] = (i < N_NODES) ? counts[i] : 0;
        s += v[j];
    }
    int pre = s;                                // inclusive wave scan
    #pragma unroll
    for (int off = 1; off < 64; off <<= 1) {
        int t = __shfl_up(pre, off);
        if (lane >= off) pre += t;
    }
    if (lane == 63) wsum[wv] = pre;
    __syncthreads();
    if (wv == 0 && lane < 16) {
        int x = wsum[lane];
        int p = x;
        #pragma unroll
        for (int off = 1; off < 16; off <<= 1) {
            int t = __shfl_up(p, off);
            if (lane >= off) p += t;
        }
        wpre[lane] = p - x;                     // exclusive wave prefix
    }
    __syncthreads();
    int excl = wpre[wv] + pre - s;              // exclusive prefix for this thread
    #pragma unroll
    for (int j = 0; j < 10; ++j) {
        int i = base + j;
        if (i < N_NODES) { offsets[i] = excl; cursors[i] = excl; }
        excl += v[j];
    }
}

// ---------------- fused CSR-order + sender permute + spherical harmonics --------
__global__ void kprep(const float* __restrict__ vec, const int* __restrict__ senders,
                      const int* __restrict__ recv, int* __restrict__ cursors,
                      int* __restrict__ order, float* __restrict__ yw,
                      int* __restrict__ ssort) {
    int e = blockIdx.x * 256 + threadIdx.x;
    int r = recv[e];
    int p = atomicAdd(&cursors[r], 1);
    order[p] = e;
    ssort[p] = senders[e];

    float x = vec[e * 3 + 0], y = vec[e * 3 + 1], z = vec[e * 3 + 2];
    float nrm = sqrtf(x * x + y * y + z * z);
    float d = 1.f / (nrm + 1e-12f);
    x *= d; y *= d; z *= d;
    const float s3  = 1.7320508075688772f;
    const float s5  = 2.2360679774997896f;
    const float s15 = 3.8729833462074170f;
    const float c33 = 2.0916500663351889f;   // sqrt(35/8)
    const float c32 = 10.246950765959598f;   // sqrt(105)
    const float c31 = 1.6201851746019651f;   // sqrt(21/8)
    const float c30 = 1.3228756555322954f;   // 0.5*sqrt(7)
    float x2 = x * x, y2 = y * y, z2 = z * z;
    float4 a, b, c, dd;
    a.x = s3 * y;  a.y = s3 * z;  a.z = s3 * x;           // Y1
    a.w = s15 * x * y;                                     // Y2[0]
    b.x = s15 * y * z;
    b.y = 0.5f * s5 * (3.f * z2 - 1.f);
    b.z = s15 * x * z;
    b.w = 0.5f * s15 * (x2 - y2);
    c.x = c33 * y * (3.f * x2 - y2);                       // Y3
    c.y = c32 * x * y * z;
    c.z = c31 * y * (5.f * z2 - 1.f);
    c.w = c30 * z * (5.f * z2 - 3.f);
    dd.x = c31 * x * (5.f * z2 - 1.f);
    dd.y = 0.5f * c32 * z * (x2 - y2);
    dd.z = c33 * x * (x2 - 3.f * y2);
    dd.w = 0.f;
    float4* yp = reinterpret_cast<float4*>(yw + (size_t)p * 16);
    yp[0] = a; yp[1] = b; yp[2] = c; yp[3] = dd;
}

// ---------------- fused 4-layer radial MLP, register-blocked --------------------
// 256-thread blocks = 4 waves; each wave owns 32 edges and a PRIVATE 8 KB
// quarter of the 32 KB LDS buffer (no barriers anywhere).
// Lane = (le in [0,8)) x (ln in [0,8)); lane owns acc[4 edges][8 channels].
// Activations: LDS, XOR-quad-swizzled (quad' = quad ^ le), updated IN-PLACE
// per layer (all kq reads complete before writes; per-wave LDS program order).
// Weights: streamed from global (L1/L2-resident, vmem pipe — off the LDS pipe).
#define MTILE 32
#define WPB   4                       // waves per block
#define BTILE (MTILE * WPB)           // 128 edges per block

__device__ __forceinline__ float silu(float v) {
    return v / (1.f + __expf(-v));
}

template<bool ACT, bool TO_LDS>
__device__ __forceinline__ void layer64(float* buf,                      // LDS [32][64] swizzled (src, and dst if TO_LDS)
                                        const float* __restrict__ W,     // global [64][N]
                                        int N, int nbase, float scale,
                                        float* __restrict__ gout,        // global (!TO_LDS), pre-offset by nbase
                                        int le, int ln) {
    float acc[4][8];
    #pragma unroll
    for (int j = 0; j < 4; ++j)
        #pragma unroll
        for (int i = 0; i < 8; ++i) acc[j][i] = 0.f;

    #pragma unroll 2
    for (int kq = 0; kq < 16; ++kq) {
        float a[4][4];
        #pragma unroll
        for (int j = 0; j < 4; ++j) {
            float4 t = *reinterpret_cast<const float4*>(
                &buf[(le * 4 + j) * 64 + ((kq ^ le) << 2)]);
            a[j][0] = t.x; a[j][1] = t.y; a[j][2] = t.z; a[j][3] = t.w;
        }
        float w[4][8];
        #pragma unroll
        for (int kk = 0; kk < 4; ++kk) {
            const float* wr = W + (size_t)(kq * 4 + kk) * N + nbase + ln * 8;
            float4 t0 = *reinterpret_cast<const float4*>(wr);
            float4 t1 = *reinterpret_cast<const float4*>(wr + 4);
            w[kk][0] = t0.x; w[kk][1] = t0.y; w[kk][2] = t0.z; w[kk][3] = t0.w;
            w[kk][4] = t1.x; w[kk][5] = t1.y; w[kk][6] = t1.z; w[kk][7] = t1.w;
        }
        #pragma unroll
        for (int j = 0; j < 4; ++j)
            #pragma unroll
            for (int kk = 0; kk < 4; ++kk)
                #pragma unroll
                for (int i = 0; i < 8; ++i)
                    acc[j][i] = fmaf(a[j][kk], w[kk][i], acc[j][i]);
    }

    // fence: keep all LDS reads above, writes below (in-place update)
    asm volatile("" ::: "memory");

    #pragma unroll
    for (int j = 0; j < 4; ++j) {
        #pragma unroll
        for (int t = 0; t < 2; ++t) {
            float v0 = acc[j][t * 4 + 0] * scale;
            float v1 = acc[j][t * 4 + 1] * scale;
            float v2 = acc[j][t * 4 + 2] * scale;
            float v3 = acc[j][t * 4 + 3] * scale;
            float4 o;
            if (ACT) { o.x = silu(v0); o.y = silu(v1); o.z = silu(v2); o.w = silu(v3); }
            else     { o.x = v0; o.y = v1; o.z = v2; o.w = v3; }
            if (TO_LDS) {
                *reinterpret_cast<float4*>(
                    &buf[(le * 4 + j) * 64 + (((2 * ln + t) ^ le) << 2)]) = o;
            } else {
                *reinterpret_cast<float4*>(
                    &gout[(size_t)(le * 4 + j) * 256 + ln * 8 + t * 4]) = o;
            }
        }
    }
}

__global__ __launch_bounds__(256) void kmlp(const float* __restrict__ radial,
                                            const int* __restrict__ order,
                                            const float* __restrict__ w1,
                                            const float* __restrict__ w2,
                                            const float* __restrict__ w3,
                                            const float* __restrict__ w4,
                                            float* __restrict__ mix, int clo) {
    __shared__ float hAs[WPB][MTILE * 64];   // 32 KB — 5 blocks/CU = 20 waves/CU
    const int tid  = threadIdx.x;
    const int lane = tid & 63;
    const int wv   = tid >> 6;
    const int ln   = lane & 7;
    const int le   = lane >> 3;
    float* hA = hAs[wv];                      // wave-private 8 KB
    const int tbase = blockIdx.x * BTILE + wv * MTILE;   // chunk-relative edge base
    const int pb    = clo + tbase;                        // global permuted position

    // edge ids for this lane's 4 edges (same across ln within an le group)
    int eid[4];
    #pragma unroll
    for (int j = 0; j < 4; ++j) eid[j] = order[pb + le * 4 + j];

    // ---- layer 1 (K=8): acts direct from global; silu((x@w1)/sqrt8) -> hA
    {
        float ax[4][8];
        #pragma unroll
        for (int j = 0; j < 4; ++j) {
            const float* rp = radial + (size_t)eid[j] * 8;
            float4 t0 = *reinterpret_cast<const float4*>(rp);
            float4 t1 = *reinterpret_cast<const float4*>(rp + 4);
            ax[j][0] = t0.x; ax[j][1] = t0.y; ax[j][2] = t0.z; ax[j][3] = t0.w;
            ax[j][4] = t1.x; ax[j][5] = t1.y; ax[j][6] = t1.z; ax[j][7] = t1.w;
        }
        float acc[4][8];
        #pragma unroll
        for (int j = 0; j < 4; ++j)
            #pragma unroll
            for (int i = 0; i < 8; ++i) acc[j][i] = 0.f;
        #pragma unroll
        for (int k = 0; k < 8; ++k) {
            const float* wr = w1 + k * 64 + ln * 8;
            float4 t0 = *reinterpret_cast<const float4*>(wr);
            float4 t1 = *reinterpret_cast<const float4*>(wr + 4);
            float w[8] = {t0.x, t0.y, t0.z, t0.w, t1.x, t1.y, t1.z, t1.w};
            #pragma unroll
            for (int j = 0; j < 4; ++j)
                #pragma unroll
                for (int i = 0; i < 8; ++i)
                    acc[j][i] = fmaf(ax[j][k], w[i], acc[j][i]);
        }
        #pragma unroll
        for (int j = 0; j < 4; ++j) {
            #pragma unroll
            for (int t = 0; t < 2; ++t) {
                float4 o;
                o.x = silu(acc[j][t * 4 + 0] * 0.35355339059327373f);
                o.y = silu(acc[j][t * 4 + 1] * 0.35355339059327373f);
                o.z = silu(acc[j][t * 4 + 2] * 0.35355339059327373f);
                o.w = silu(acc[j][t * 4 + 3] * 0.35355339059327373f);
                *reinterpret_cast<float4*>(
                    &hA[(le * 4 + j) * 64 + (((2 * ln + t) ^ le) << 2)]) = o;
            }
        }
    }

    // ---- layers 2,3: 64->64, silu, LDS in-place
    layer64<true, true>(hA, w2, 64, 0, 0.125f, nullptr, le, ln);
    layer64<true, true>(hA, w3, 64, 0, 0.125f, nullptr, le, ln);

    // ---- layer 4: 64->256, no act, -> mix (chunk-relative)
    float* gbase = mix + (size_t)tbase * 256;
    #pragma unroll
    for (int jg = 0; jg < 4; ++jg)
        layer64<false, false>(hA, w4, 256, jg * 64, 0.125f, gbase + jg * 64, le, ln);
}

// ---------------- per-node gather/accumulate (sequential mix/yw/ssort reads) ----
__global__ __launch_bounds__(256) void kgather(const float* __restrict__ mix,
                                               const float* __restrict__ yw,
                                               const int* __restrict__ ssort,
                                               const float* __restrict__ node_feats,
                                               const int* __restrict__ offsets,
                                               const int* __restrict__ counts,
                                               float* __restrict__ out,
                                               int clo, int chi) {
    __shared__ float so[4][1024];
    const int lane = threadIdx.x & 63;
    const int wv   = threadIdx.x >> 6;
    const int n    = blockIdx.x * 4 + wv;   // grid is exactly N_NODES/4

    const int start = offsets[n];
    const int cnt   = counts[n];
    const int end   = start + cnt;
    const int s0    = (start > clo) ? start : clo;
    const int s1    = (end < chi) ? end : chi;

    float a0 = 0.f;
    float a1[3] = {0.f, 0.f, 0.f};
    float a2[5] = {0.f, 0.f, 0.f, 0.f, 0.f};
    float a3[7] = {0.f, 0.f, 0.f, 0.f, 0.f, 0.f, 0.f};

    int i = s0;
    for (; i + 2 <= s1; i += 2) {
        const int sA = ssort[i];
        const int sB = ssort[i + 1];
        const float* mpA = mix + (size_t)(i - clo) * 256;
        const float* mpB = mpA + 256;
        const float fA = node_feats[sA * 64 + lane];
        const float fB = node_feats[sB * 64 + lane];
        const float4* ypA = reinterpret_cast<const float4*>(yw + (size_t)i * 16);
        const float4* ypB = ypA + 4;
        const float4 yaA = ypA[0], ybA = ypA[1], ycA = ypA[2], ydA = ypA[3];
        const float4 yaB = ypB[0], ybB = ypB[1], ycB = ypB[2], ydB = ypB[3];
        const float t0A = fA * mpA[lane],       t0B = fB * mpB[lane];
        const float t1A = fA * mpA[64 + lane],  t1B = fB * mpB[64 + lane];
        const float t2A = fA * mpA[128 + lane], t2B = fB * mpB[128 + lane];
        const float t3A = fA * mpA[192 + lane], t3B = fB * mpB[192 + lane];
        a0 += t0A + t0B;
        a1[0] += t1A * yaA.x + t1B * yaB.x;
        a1[1] += t1A * yaA.y + t1B * yaB.y;
        a1[2] += t1A * yaA.z + t1B * yaB.z;
        a2[0] += t2A * yaA.w + t2B * yaB.w;
        a2[1] += t2A * ybA.x + t2B * ybB.x;
        a2[2] += t2A * ybA.y + t2B * ybB.y;
        a2[3] += t2A * ybA.z + t2B * ybB.z;
        a2[4] += t2A * ybA.w + t2B * ybB.w;
        a3[0] += t3A * ycA.x + t3B * ycB.x;
        a3[1] += t3A * ycA.y + t3B * ycB.y;
        a3[2] += t3A * ycA.z + t3B * ycB.z;
        a3[3] += t3A * ycA.w + t3B * ycB.w;
        a3[4] += t3A * ydA.x + t3B * ydB.x;
        a3[5] += t3A * ydA.y + t3B * ydB.y;
        a3[6] += t3A * ydA.z + t3B * ydB.z;
    }
    if (i < s1) {
        const int sA = ssort[i];
        const float* mpA = mix + (size_t)(i - clo) * 256;
        const float fA = node_feats[sA * 64 + lane];
        const float4* ypA = reinterpret_cast<const float4*>(yw + (size_t)i * 16);
        const float4 yaA = ypA[0], ybA = ypA[1], ycA = ypA[2], ydA = ypA[3];
        const float t0A = fA * mpA[lane];
        const float t1A = fA * mpA[64 + lane];
        const float t2A = fA * mpA[128 + lane];
        const float t3A = fA * mpA[192 + lane];
        a0 += t0A;
        a1[0] += t1A * yaA.x; a1[1] += t1A * yaA.y; a1[2] += t1A * yaA.z;
        a2[0] += t2A * yaA.w; a2[1] += t2A * ybA.x; a2[2] += t2A * ybA.y;
        a2[3] += t2A * ybA.z; a2[4] += t2A * ybA.w;
        a3[0] += t3A * ycA.x; a3[1] += t3A * ycA.y; a3[2] += t3A * ycA.z;
        a3[3] += t3A * ycA.w; a3[4] += t3A * ydA.x; a3[5] += t3A * ydA.y;
        a3[6] += t3A * ydA.z;
    }

    // stage irrep-strided layout in LDS (wave-private), then coalesced store
    so[wv][lane] = a0;
    #pragma unroll
    for (int j = 0; j < 3; ++j) so[wv][64  + lane * 3 + j] = a1[j];
    #pragma unroll
    for (int j = 0; j < 5; ++j) so[wv][256 + lane * 5 + j] = a2[j];
    #pragma unroll
    for (int j = 0; j < 7; ++j) so[wv][576 + lane * 7 + j] = a3[j];

    float* op = out + (size_t)n * 1024;
    if (start >= clo) {           // chunk holds the node's first edge: store
        #pragma unroll
        for (int k = 0; k < 16; ++k)
            op[k * 64 + lane] = so[wv][k * 64 + lane] * 0.25f;   // 1/sqrt(16)
    } else if (s1 > s0) {         // continuation chunk: accumulate
        #pragma unroll
        for (int k = 0; k < 16; ++k)
            op[k * 64 + lane] += so[wv][k * 64 + lane] * 0.25f;
    }
}

// ---------------- launch ----------------
extern "C" void kernel_launch(void* const* d_in, const int* in_sizes, int n_in,
                              void* d_out, int out_size, void* d_ws, size_t ws_size,
                              hipStream_t stream) {
    const float* vectors    = (const float*)d_in[0];
    const float* node_feats = (const float*)d_in[1];
    const float* radial     = (const float*)d_in[2];
    const float* w1         = (const float*)d_in[3];
    const float* w2         = (const float*)d_in[4];
    const float* w3         = (const float*)d_in[5];
    const float* w4         = (const float*)d_in[6];
    const int*   senders    = (const int*)d_in[7];
    const int*   receivers  = (const int*)d_in[8];
    float*       out        = (float*)d_out;

    char* ws = (char*)d_ws;
    int*   counts  = (int*)(ws);
    int*   offsets = (int*)(ws + OFF_OFFSETS);
    int*   cursors = (int*)(ws + OFF_CURSORS);
    int*   order   = (int*)(ws + OFF_ORDER);
    float* yw      = (float*)(ws + OFF_Y);
    int*   ssort   = (int*)(ws + OFF_SSORT);
    float* mix     = (float*)(ws + OFF_MIX);

    // adaptive mix chunking from ws_size (constant per session -> graph-safe)
    size_t avail = (ws_size > (size_t)OFF_MIX) ? ws_size - (size_t)OFF_MIX : 0;
    long maxE = (long)(avail / (256 * 4));
    maxE -= maxE % BTILE;
    if (maxE < BTILE) maxE = BTILE;
    if (maxE > N_EDGES) maxE = N_EDGES;
    const int nch = (int)((N_EDGES + maxE - 1) / maxE);

    hipMemsetAsync(counts, 0, N_NODES * sizeof(int), stream);
    if (nch > 1)
        hipMemsetAsync(out, 0, (size_t)out_size * sizeof(float), stream);
    khist <<<N_EDGES / 256, 256, 0, stream>>>(receivers, counts);
    kscan <<<1, 1024, 0, stream>>>(counts, offsets, cursors);
    kprep <<<N_EDGES / 256, 256, 0, stream>>>(vectors, senders, receivers, cursors,
                                              order, yw, ssort);

    for (int c = 0; c < nch; ++c) {
        const int clo = (int)((long)c * maxE);
        const int chi = (int)(((long)clo + maxE < N_EDGES) ? clo + maxE : N_EDGES);
        kmlp   <<<(chi - clo) / BTILE, 256, 0, stream>>>(radial, order, w1, w2, w3, w4,
                                                         mix, clo);
        kgather<<<N_NODES / 4, 256, 0, stream>>>(mix, yw, ssort, node_feats,
                                                 offsets, counts, out, clo, chi);
    }
}